// Round 7
// baseline (176.065 us; speedup 1.0000x reference)
//
#include <hip/hip_runtime.h>
#include <stddef.h>

#define N_NODES 10000
#define NE 320000
#define NB 32
#define SIZE1 80000
#define SIZE2 80000
#define CAP 96          // fixed CSR capacity per node; deg ~ Poisson(32), P(>96) ~ 1e-20
#define CSTRIDE 32      // cursor padding: 1 counter per 128B L2 line (r6: -9us win)

// d_ws layout (int offsets)
#define WS_CURSOR 0          // int[N_NODES*CSTRIDE] = 320000 ints (1.28 MB, padded)
#define WS_RECS   320000     // ulong recs[N_NODES*CAP] = 1.92M ints (byte 1280000, 8B aligned)
#define WS_XT     2240000    // bf16 xt[N_NODES][32][8] = 1.28M ints (byte 8960000, 16B aligned)

typedef short short8 __attribute__((ext_vector_type(8)));
typedef float floatx4 __attribute__((ext_vector_type(4)));
union FragU { short8 v; ushort us[8]; uint4 u4; };

__device__ inline ushort f2bf(float f) {
  union { float f; unsigned u; } c; c.f = f;
  unsigned u = c.u;
  u += 0x7fffu + ((u >> 16) & 1u);   // round-to-nearest-even
  return (ushort)(u >> 16);
}

__device__ inline unsigned pack2bf(float a, float b) {
  return (unsigned)f2bf(a) | ((unsigned)f2bf(b) << 16);
}

// Build kernel — unchanged from r6 (winner):
//  1) CSR scatter: atomicAdd cursor[row*CSTRIDE] -> one 8B record {e, col}.
//  2) x fp32->bf16 transpose xt[n][b][i], LDS-free, (n,b) = (g>>5, g&31).
__global__ __launch_bounds__(256) void build_kernel(const float* __restrict__ x,
                                                    const int* __restrict__ idxs,
                                                    int* __restrict__ cursor,
                                                    unsigned long long* __restrict__ recs,
                                                    ushort* __restrict__ xt) {
  const int t = threadIdx.x;
  const int g = blockIdx.x * 256 + t;            // NE = 1250*256 exactly
  // transpose task loads first (independent of the atomic chain)
  const int n = g >> 5;
  const int b = g & 31;
  const float* xp = x + (size_t)b * SIZE1 + n * 8;
  const float4 v0 = *(const float4*)xp;
  const float4 v1 = *(const float4*)(xp + 4);

  // CSR scatter (padded cursor: 1 counter per 128B line)
  const int r = idxs[g];
  const int c = idxs[NE + g];
  const int pos = atomicAdd(&cursor[r * CSTRIDE], 1);
  if (pos < CAP)
    recs[(size_t)r * CAP + pos] = (unsigned long long)(unsigned)g |
                                  ((unsigned long long)(unsigned)c << 32);

  // finish transpose
  FragU f;
  f.us[0] = f2bf(v0.x); f.us[1] = f2bf(v0.y); f.us[2] = f2bf(v0.z); f.us[3] = f2bf(v0.w);
  f.us[4] = f2bf(v1.x); f.us[5] = f2bf(v1.y); f.us[6] = f2bf(v1.z); f.us[7] = f2bf(v1.w);
  *(uint4*)(xt + (size_t)n * 256 + b * 8) = f.u4;
}

// ONE WAVE PER NODE (4 nodes per 256-block).
// r7 changes (gather only):
//  - per-quad direct recs loads (16-lane broadcast, L1-resident) replace the
//    64-lane chunk load + 4 index shuffles.
//  - B-transpose via per-wave LDS staging: 1 ds_write_b64 + 8 ds_read_b32
//    per slot (was 16 ds_bpermute + selects). DS ops/iter: 36 -> 18.
//    Quad regions padded to 34 dwords so read banks = quad*2 + i*4 + p*2 + selW
//    (~2-way conflicts, free). Private region per wave -> no barriers; same-wave
//    DS ordering makes write->read safe across iterations.
__global__ __launch_bounds__(256) void gather_mfma_kernel(const ushort* __restrict__ xt,
                                                          const float* __restrict__ vals,
                                                          const float* __restrict__ bias,
                                                          const int* __restrict__ cursor,
                                                          const unsigned long long* __restrict__ recs,
                                                          float* __restrict__ out) {
  __shared__ unsigned ldsb[4][2][136];   // [wave][slot-of-pair][4 quads * 34 dwords]
  const int t = threadIdx.x;
  const int lane = t & 63;
  const int w = t >> 6;              // wave id 0..3
  const int n = blockIdx.x * 4 + w;  // node for this wave
  const int quad = lane >> 4;
  const int nn = lane & 15;
  const int deg = min(cursor[n * CSTRIDE], CAP);
  const size_t nbase = (size_t)n * CAP;

  // B-layout geometry: dest lane (quad,nn) needs v[edge_quad][i][j=nn&7]:
  // source dword sits at LDS dword (quad*34 + (i*2+p)*2 + selW), half selH,
  // where p=(nn>>2)&1, selW=(nn>>1)&1, selH=nn&1.
  const int p = (nn >> 2) & 1;
  const int selW = (nn >> 1) & 1;
  const bool selH = (nn & 1) != 0;
  const int rbase = quad * 34 + p * 2 + selW;   // + i*4 per i
  const int wbase = quad * 34 + nn * 2;         // this lane's 2-dword write slot

  unsigned* L0 = &ldsb[w][0][0];
  unsigned* L1 = &ldsb[w][1][0];

  floatx4 acc0 = {0.f, 0.f, 0.f, 0.f};
  floatx4 acc1 = {0.f, 0.f, 0.f, 0.f};

  for (int base = 0; base < deg; base += 64) {
    const int lim = min(64, deg - base);                       // edges this chunk
    const int nslots = (lim + 3) >> 2;                         // 4-edge slots

    for (int s = 0; s < nslots; s += 2) {
      const int le0 = s * 4 + quad;
      const int le1 = le0 + 4;
      const bool ok0 = le0 < lim;
      const bool ok1 = le1 < lim;
      // per-quad record loads (broadcast within quad; node's recs are L1-hot)
      const unsigned long long r0 = recs[nbase + base + min(le0, lim - 1)];
      const unsigned long long r1 = recs[nbase + base + min(le1, lim - 1)];
      const int eid0 = (int)(unsigned)r0;
      const int px0  = (int)(unsigned)(r0 >> 32);
      const int eid1 = (int)(unsigned)r1;
      const int px1  = (int)(unsigned)(r1 >> 32);

      // issue all global loads up front
      const float4 f0 = *(const float4*)(vals + (size_t)eid0 * 64 + nn * 4);  // 1KB/slot coalesced
      const float4 f1 = *(const float4*)(vals + (size_t)eid1 * 64 + nn * 4);
      const ushort* xr0 = xt + (size_t)px0 * 256;
      const ushort* xr1 = xt + (size_t)px1 * 256;
      FragU alo0, ahi0, alo1, ahi1;
      alo0.u4 = *(const uint4*)(xr0 + nn * 8);                // batch = nn
      ahi0.u4 = *(const uint4*)(xr0 + 128 + nn * 8);          // batch = nn+16
      alo1.u4 = *(const uint4*)(xr1 + nn * 8);
      ahi1.u4 = *(const uint4*)(xr1 + 128 + nn * 8);

      // convert + zero invalid edges (keeps B exactly 0)
      unsigned u00 = pack2bf(f0.x, f0.y), u01 = pack2bf(f0.z, f0.w);
      unsigned u10 = pack2bf(f1.x, f1.y), u11 = pack2bf(f1.z, f1.w);
      if (!ok0) { u00 = 0; u01 = 0; }
      if (!ok1) { u10 = 0; u11 = 0; }

      // stage both slots to LDS (8B aligned: wbase*4 = quad*136 + nn*8)
      *(uint2*)&L0[wbase] = make_uint2(u00, u01);
      *(uint2*)&L1[wbase] = make_uint2(u10, u11);

      // gather columns: 8 ds_read_b32 per frag, half-select in VALU
      FragU b0, b1;
#pragma unroll
      for (int i = 0; i < 8; ++i) {
        const unsigned w0 = L0[rbase + i * 4];
        const unsigned w1 = L1[rbase + i * 4];
        b0.us[i] = selH ? (ushort)(w0 >> 16) : (ushort)(w0 & 0xffffu);
        b1.us[i] = selH ? (ushort)(w1 >> 16) : (ushort)(w1 & 0xffffu);
      }

      acc0 = __builtin_amdgcn_mfma_f32_16x16x32_bf16(alo0.v, b0.v, acc0, 0, 0, 0);
      acc1 = __builtin_amdgcn_mfma_f32_16x16x32_bf16(ahi0.v, b0.v, acc1, 0, 0, 0);
      acc0 = __builtin_amdgcn_mfma_f32_16x16x32_bf16(alo1.v, b1.v, acc0, 0, 0, 0);
      acc1 = __builtin_amdgcn_mfma_f32_16x16x32_bf16(ahi1.v, b1.v, acc1, 0, 0, 0);
    }
  }

  // C/D: col(j) = lane&15, row(b) = quad*4 + reg. Each wave writes its node.
  if (nn < 8) {
    const float bz = bias[n * 8 + nn];
#pragma unroll
    for (int r = 0; r < 4; ++r) {
      out[(size_t)(quad * 4 + r) * SIZE2 + n * 8 + nn] = acc0[r] + bz;
      out[(size_t)(16 + quad * 4 + r) * SIZE2 + n * 8 + nn] = acc1[r] + bz;
    }
  }
}

extern "C" void kernel_launch(void* const* d_in, const int* in_sizes, int n_in,
                              void* d_out, int out_size, void* d_ws, size_t ws_size,
                              hipStream_t stream) {
  const float* x    = (const float*)d_in[0];
  const float* vals = (const float*)d_in[1];
  const float* bias = (const float*)d_in[2];
  const int*   idxs = (const int*)d_in[3];
  float* out = (float*)d_out;

  int* ws = (int*)d_ws;
  int* cursor = ws + WS_CURSOR;
  unsigned long long* recs = (unsigned long long*)(ws + WS_RECS);
  ushort* xt = (ushort*)(ws + WS_XT);

  hipMemsetAsync(cursor, 0, N_NODES * CSTRIDE * sizeof(int), stream);

  build_kernel<<<NE / 256, 256, 0, stream>>>(x, idxs, cursor, recs, xt);
  gather_mfma_kernel<<<N_NODES / 4, 256, 0, stream>>>(xt, vals, bias, cursor, recs, out);
}

// Round 8
// 168.526 us; speedup vs baseline: 1.0447x; 1.0447x over previous
//
#include <hip/hip_runtime.h>
#include <stddef.h>

#define N_NODES 10000
#define NE 320000
#define NB 32
#define SIZE1 80000
#define SIZE2 80000
#define CAP 96          // fixed CSR capacity per node; deg ~ Poisson(32), P(>96) ~ 1e-20
#define CSTRIDE 32      // cursor padding: 1 counter per 128B L2 line (r6: -9us win)

// d_ws layout (int offsets)
#define WS_CURSOR 0          // int[N_NODES*CSTRIDE] = 320000 ints (1.28 MB, padded)
#define WS_RECS   320000     // ulong recs[N_NODES*CAP] = 1.92M ints (byte 1280000, 8B aligned)
#define WS_XT     2240000    // bf16 xt[N_NODES][32][8] = 1.28M ints (byte 8960000, 16B aligned)

typedef short short8 __attribute__((ext_vector_type(8)));
typedef float floatx4 __attribute__((ext_vector_type(4)));
union FragU { short8 v; ushort us[8]; uint4 u4; };

__device__ inline ushort f2bf(float f) {
  union { float f; unsigned u; } c; c.f = f;
  unsigned u = c.u;
  u += 0x7fffu + ((u >> 16) & 1u);   // round-to-nearest-even
  return (ushort)(u >> 16);
}

__device__ inline unsigned pack2bf(float a, float b) {
  return (unsigned)f2bf(a) | ((unsigned)f2bf(b) << 16);
}

// Build kernel — unchanged from r6 (winner):
//  1) CSR scatter: atomicAdd cursor[row*CSTRIDE] -> one 8B record {e, col}.
//  2) x fp32->bf16 transpose xt[n][b][i], LDS-free, (n,b) = (g>>5, g&31).
__global__ __launch_bounds__(256) void build_kernel(const float* __restrict__ x,
                                                    const int* __restrict__ idxs,
                                                    int* __restrict__ cursor,
                                                    unsigned long long* __restrict__ recs,
                                                    ushort* __restrict__ xt) {
  const int t = threadIdx.x;
  const int g = blockIdx.x * 256 + t;            // NE = 1250*256 exactly
  // transpose task loads first (independent of the atomic chain)
  const int n = g >> 5;
  const int b = g & 31;
  const float* xp = x + (size_t)b * SIZE1 + n * 8;
  const float4 v0 = *(const float4*)xp;
  const float4 v1 = *(const float4*)(xp + 4);

  // CSR scatter (padded cursor: 1 counter per 128B line)
  const int r = idxs[g];
  const int c = idxs[NE + g];
  const int pos = atomicAdd(&cursor[r * CSTRIDE], 1);
  if (pos < CAP)
    recs[(size_t)r * CAP + pos] = (unsigned long long)(unsigned)g |
                                  ((unsigned long long)(unsigned)c << 32);

  // finish transpose
  FragU f;
  f.us[0] = f2bf(v0.x); f.us[1] = f2bf(v0.y); f.us[2] = f2bf(v0.z); f.us[3] = f2bf(v0.w);
  f.us[4] = f2bf(v1.x); f.us[5] = f2bf(v1.y); f.us[6] = f2bf(v1.z); f.us[7] = f2bf(v1.w);
  *(uint4*)(xt + (size_t)n * 256 + b * 8) = f.u4;
}

// ONE WAVE PER NODE (4 nodes per 256-block) — r6's proven structure (shfl
// indices + register bpermute transpose, NO LDS; r7's LDS staging + broadcast
// recs loads regressed: 1.4M bank conflicts + per-iter VMEM->VMEM chain).
// r8 single change: 4 slots per iteration (was 2) — 16 VMEM loads in flight,
// halving the serialized latency rounds per wave (deg~32: 4 -> 2 rounds).
// VGPR ~28 -> ~90, still under the 128 tier; occupancy unaffected.
__global__ __launch_bounds__(256) void gather_mfma_kernel(const ushort* __restrict__ xt,
                                                          const float* __restrict__ vals,
                                                          const float* __restrict__ bias,
                                                          const int* __restrict__ cursor,
                                                          const unsigned long long* __restrict__ recs,
                                                          float* __restrict__ out) {
  const int t = threadIdx.x;
  const int lane = t & 63;
  const int w = t >> 6;              // wave id 0..3
  const int n = blockIdx.x * 4 + w;  // node for this wave
  const int quad = lane >> 4;
  const int nn = lane & 15;
  const int deg = min(cursor[n * CSTRIDE], CAP);
  const size_t nbase = (size_t)n * CAP;

  // Loop-invariant shuffle geometry.
  const int laneBase = lane & 48;            // quad*16
  const int p = (nn >> 2) & 1;               // which 16B half of the edge row-pair
  const bool selW = (nn & 2) != 0;           // which packed word
  const bool selH = (nn & 1) != 0;           // which half of the word
  int sidx[8];
#pragma unroll
  for (int i = 0; i < 8; ++i) sidx[i] = laneBase | (i << 1) | p;

  floatx4 acc0 = {0.f, 0.f, 0.f, 0.f};
  floatx4 acc1 = {0.f, 0.f, 0.f, 0.f};

  for (int base = 0; base < deg; base += 64) {
    const int lim = min(64, deg - base);                       // edges this chunk
    const unsigned long long rv = recs[nbase + base + min(lane, lim - 1)];  // coalesced
    const int elo = (int)(unsigned)rv;                         // edge id
    const int ehi = (int)(unsigned)(rv >> 32);                 // col (x node)
    const int nslots = (lim + 3) >> 2;                         // 4-edge slots

    for (int s = 0; s < nslots; s += 4) {
      // --- indices for 4 slots (cheap shfls) ---
      const int le0 = (s + 0) * 4 + quad;
      const int le1 = (s + 1) * 4 + quad;
      const int le2 = (s + 2) * 4 + quad;
      const int le3 = (s + 3) * 4 + quad;
      const int lec0 = min(le0, lim - 1), lec1 = min(le1, lim - 1);
      const int lec2 = min(le2, lim - 1), lec3 = min(le3, lim - 1);
      const int eid0 = __shfl(elo, lec0), px0 = __shfl(ehi, lec0);
      const int eid1 = __shfl(elo, lec1), px1 = __shfl(ehi, lec1);
      const int eid2 = __shfl(elo, lec2), px2 = __shfl(ehi, lec2);
      const int eid3 = __shfl(elo, lec3), px3 = __shfl(ehi, lec3);
      const bool ok0 = le0 < lim, ok1 = le1 < lim, ok2 = le2 < lim, ok3 = le3 < lim;

      // --- issue ALL 16 global loads up front (latency overlap) ---
      const float4 f0 = *(const float4*)(vals + (size_t)eid0 * 64 + nn * 4);  // 1KB/slot coalesced
      const float4 f1 = *(const float4*)(vals + (size_t)eid1 * 64 + nn * 4);
      const float4 f2 = *(const float4*)(vals + (size_t)eid2 * 64 + nn * 4);
      const float4 f3 = *(const float4*)(vals + (size_t)eid3 * 64 + nn * 4);
      const ushort* xr0 = xt + (size_t)px0 * 256;
      const ushort* xr1 = xt + (size_t)px1 * 256;
      const ushort* xr2 = xt + (size_t)px2 * 256;
      const ushort* xr3 = xt + (size_t)px3 * 256;
      FragU alo0, ahi0, alo1, ahi1, alo2, ahi2, alo3, ahi3;
      alo0.u4 = *(const uint4*)(xr0 + nn * 8);                // batch = nn
      ahi0.u4 = *(const uint4*)(xr0 + 128 + nn * 8);          // batch = nn+16
      alo1.u4 = *(const uint4*)(xr1 + nn * 8);
      ahi1.u4 = *(const uint4*)(xr1 + 128 + nn * 8);
      alo2.u4 = *(const uint4*)(xr2 + nn * 8);
      ahi2.u4 = *(const uint4*)(xr2 + 128 + nn * 8);
      alo3.u4 = *(const uint4*)(xr3 + nn * 8);
      ahi3.u4 = *(const uint4*)(xr3 + 128 + nn * 8);

      // --- convert + zero invalid edges (keeps B exactly 0) ---
      unsigned u00 = pack2bf(f0.x, f0.y), u01 = pack2bf(f0.z, f0.w);
      unsigned u10 = pack2bf(f1.x, f1.y), u11 = pack2bf(f1.z, f1.w);
      unsigned u20 = pack2bf(f2.x, f2.y), u21 = pack2bf(f2.z, f2.w);
      unsigned u30 = pack2bf(f3.x, f3.y), u31 = pack2bf(f3.z, f3.w);
      if (!ok0) { u00 = 0; u01 = 0; }
      if (!ok1) { u10 = 0; u11 = 0; }
      if (!ok2) { u20 = 0; u21 = 0; }
      if (!ok3) { u30 = 0; u31 = 0; }

      // --- in-wave transpose to B layout: lane nn <- column j=nn ---
      FragU b0, b1, b2, b3;
#pragma unroll
      for (int i = 0; i < 8; ++i) {
        unsigned t00 = (unsigned)__shfl((int)u00, sidx[i]);
        unsigned t01 = (unsigned)__shfl((int)u01, sidx[i]);
        unsigned w0 = selW ? t01 : t00;
        b0.us[i] = selH ? (ushort)(w0 >> 16) : (ushort)(w0 & 0xffffu);
        unsigned t10 = (unsigned)__shfl((int)u10, sidx[i]);
        unsigned t11 = (unsigned)__shfl((int)u11, sidx[i]);
        unsigned w1 = selW ? t11 : t10;
        b1.us[i] = selH ? (ushort)(w1 >> 16) : (ushort)(w1 & 0xffffu);
        unsigned t20 = (unsigned)__shfl((int)u20, sidx[i]);
        unsigned t21 = (unsigned)__shfl((int)u21, sidx[i]);
        unsigned w2 = selW ? t21 : t20;
        b2.us[i] = selH ? (ushort)(w2 >> 16) : (ushort)(w2 & 0xffffu);
        unsigned t30 = (unsigned)__shfl((int)u30, sidx[i]);
        unsigned t31 = (unsigned)__shfl((int)u31, sidx[i]);
        unsigned w3 = selW ? t31 : t30;
        b3.us[i] = selH ? (ushort)(w3 >> 16) : (ushort)(w3 & 0xffffu);
      }

      acc0 = __builtin_amdgcn_mfma_f32_16x16x32_bf16(alo0.v, b0.v, acc0, 0, 0, 0);
      acc1 = __builtin_amdgcn_mfma_f32_16x16x32_bf16(ahi0.v, b0.v, acc1, 0, 0, 0);
      acc0 = __builtin_amdgcn_mfma_f32_16x16x32_bf16(alo1.v, b1.v, acc0, 0, 0, 0);
      acc1 = __builtin_amdgcn_mfma_f32_16x16x32_bf16(ahi1.v, b1.v, acc1, 0, 0, 0);
      acc0 = __builtin_amdgcn_mfma_f32_16x16x32_bf16(alo2.v, b2.v, acc0, 0, 0, 0);
      acc1 = __builtin_amdgcn_mfma_f32_16x16x32_bf16(ahi2.v, b2.v, acc1, 0, 0, 0);
      acc0 = __builtin_amdgcn_mfma_f32_16x16x32_bf16(alo3.v, b3.v, acc0, 0, 0, 0);
      acc1 = __builtin_amdgcn_mfma_f32_16x16x32_bf16(ahi3.v, b3.v, acc1, 0, 0, 0);
    }
  }

  // C/D: col(j) = lane&15, row(b) = quad*4 + reg. Each wave writes its node.
  if (nn < 8) {
    const float bz = bias[n * 8 + nn];
#pragma unroll
    for (int r = 0; r < 4; ++r) {
      out[(size_t)(quad * 4 + r) * SIZE2 + n * 8 + nn] = acc0[r] + bz;
      out[(size_t)(16 + quad * 4 + r) * SIZE2 + n * 8 + nn] = acc1[r] + bz;
    }
  }
}

extern "C" void kernel_launch(void* const* d_in, const int* in_sizes, int n_in,
                              void* d_out, int out_size, void* d_ws, size_t ws_size,
                              hipStream_t stream) {
  const float* x    = (const float*)d_in[0];
  const float* vals = (const float*)d_in[1];
  const float* bias = (const float*)d_in[2];
  const int*   idxs = (const int*)d_in[3];
  float* out = (float*)d_out;

  int* ws = (int*)d_ws;
  int* cursor = ws + WS_CURSOR;
  unsigned long long* recs = (unsigned long long*)(ws + WS_RECS);
  ushort* xt = (ushort*)(ws + WS_XT);

  hipMemsetAsync(cursor, 0, N_NODES * CSTRIDE * sizeof(int), stream);

  build_kernel<<<NE / 256, 256, 0, stream>>>(x, idxs, cursor, recs, xt);
  gather_mfma_kernel<<<N_NODES / 4, 256, 0, stream>>>(xt, vals, bias, cursor, recs, out);
}

// Round 9
// 163.751 us; speedup vs baseline: 1.0752x; 1.0292x over previous
//
#include <hip/hip_runtime.h>
#include <stddef.h>

#define N_NODES 10000
#define NE 320000
#define NB 32
#define SIZE1 80000
#define SIZE2 80000
#define CAP 96          // fixed CSR capacity per node; deg ~ Poisson(32), P(>96) ~ 1e-20
#define CSTRIDE 32      // cursor padding: 1 counter per 128B L2 line (r6: -9us win)

// d_ws layout (int offsets)
#define WS_CURSOR 0          // int[N_NODES*CSTRIDE] = 320000 ints (1.28 MB, padded)
#define WS_RECS   320000     // ulong recs[N_NODES*CAP] = 1.92M ints (byte 1280000, 8B aligned)
#define WS_XT     2240000    // bf16 xt[N_NODES][32][8] = 1.28M ints (byte 8960000, 16B aligned)

typedef short short8 __attribute__((ext_vector_type(8)));
typedef float floatx4 __attribute__((ext_vector_type(4)));
union FragU { short8 v; ushort us[8]; uint4 u4; };

__device__ inline ushort f2bf(float f) {
  union { float f; unsigned u; } c; c.f = f;
  unsigned u = c.u;
  u += 0x7fffu + ((u >> 16) & 1u);   // round-to-nearest-even
  return (ushort)(u >> 16);
}

__device__ inline unsigned pack2bf(float a, float b) {
  return (unsigned)f2bf(a) | ((unsigned)f2bf(b) << 16);
}

// Build kernel — unchanged from r6 (winner):
//  1) CSR scatter: atomicAdd cursor[row*CSTRIDE] -> one 8B record {e, col}.
//  2) x fp32->bf16 transpose xt[n][b][i], LDS-free, (n,b) = (g>>5, g&31).
__global__ __launch_bounds__(256) void build_kernel(const float* __restrict__ x,
                                                    const int* __restrict__ idxs,
                                                    int* __restrict__ cursor,
                                                    unsigned long long* __restrict__ recs,
                                                    ushort* __restrict__ xt) {
  const int t = threadIdx.x;
  const int g = blockIdx.x * 256 + t;            // NE = 1250*256 exactly
  // transpose task loads first (independent of the atomic chain)
  const int n = g >> 5;
  const int b = g & 31;
  const float* xp = x + (size_t)b * SIZE1 + n * 8;
  const float4 v0 = *(const float4*)xp;
  const float4 v1 = *(const float4*)(xp + 4);

  // CSR scatter (padded cursor: 1 counter per 128B line)
  const int r = idxs[g];
  const int c = idxs[NE + g];
  const int pos = atomicAdd(&cursor[r * CSTRIDE], 1);
  if (pos < CAP)
    recs[(size_t)r * CAP + pos] = (unsigned long long)(unsigned)g |
                                  ((unsigned long long)(unsigned)c << 32);

  // finish transpose
  FragU f;
  f.us[0] = f2bf(v0.x); f.us[1] = f2bf(v0.y); f.us[2] = f2bf(v0.z); f.us[3] = f2bf(v0.w);
  f.us[4] = f2bf(v1.x); f.us[5] = f2bf(v1.y); f.us[6] = f2bf(v1.z); f.us[7] = f2bf(v1.w);
  *(uint4*)(xt + (size_t)n * 256 + b * 8) = f.u4;
}

// ONE WAVE PER NODE (4 nodes per 256-block) — r6's proven hot loop (2-slot,
// shfl indices + register shuffle-transpose, VGPR=28 -> 8 waves/SIMD TLP;
// r8 showed widening to 4-slot costs occupancy and regresses).
// r9 single change: LDS-staged COALESCED output epilogue. r6 wrote out in
// 32B sub-line granules (4 scattered segments/instr, row stride 320KB) ->
// write-allocate RFO on every 64B line (~10MB extra FETCH). The block's 4
// nodes cover 32 consecutive out columns, so stage 4KB in LDS and write
// 32 rows x 128B contiguous float4 (full lines, no RFO), bias fused.
__global__ __launch_bounds__(256) void gather_mfma_kernel(const ushort* __restrict__ xt,
                                                          const float* __restrict__ vals,
                                                          const float* __restrict__ bias,
                                                          const int* __restrict__ cursor,
                                                          const unsigned long long* __restrict__ recs,
                                                          float* __restrict__ out) {
  __shared__ float so[32][33];       // [batch row][block-local col], +1 pad
  const int t = threadIdx.x;
  const int lane = t & 63;
  const int w = t >> 6;              // wave id 0..3
  const int n = blockIdx.x * 4 + w;  // node for this wave
  const int quad = lane >> 4;
  const int nn = lane & 15;
  const int deg = min(cursor[n * CSTRIDE], CAP);
  const size_t nbase = (size_t)n * CAP;

  // Loop-invariant shuffle geometry.
  const int laneBase = lane & 48;            // quad*16
  const int p = (nn >> 2) & 1;               // which 16B half of the edge row-pair
  const bool selW = (nn & 2) != 0;           // which packed word
  const bool selH = (nn & 1) != 0;           // which half of the word
  int sidx[8];
#pragma unroll
  for (int i = 0; i < 8; ++i) sidx[i] = laneBase | (i << 1) | p;

  floatx4 acc0 = {0.f, 0.f, 0.f, 0.f};
  floatx4 acc1 = {0.f, 0.f, 0.f, 0.f};

  for (int base = 0; base < deg; base += 64) {
    const int lim = min(64, deg - base);                       // edges this chunk
    const unsigned long long rv = recs[nbase + base + min(lane, lim - 1)];  // coalesced
    const int elo = (int)(unsigned)rv;                         // edge id
    const int ehi = (int)(unsigned)(rv >> 32);                 // col (x node)
    const int nslots = (lim + 3) >> 2;                         // 4-edge slots

    for (int s = 0; s < nslots; s += 2) {
      // --- issue all global loads for both slots first (ILP) ---
      const int le0 = s * 4 + quad;
      const int lec0 = min(le0, lim - 1);
      const int eid0 = __shfl(elo, lec0);
      const int px0  = __shfl(ehi, lec0);
      const bool ok0 = le0 < lim;
      const int le1 = (s + 1) * 4 + quad;
      const int lec1 = min(le1, lim - 1);
      const int eid1 = __shfl(elo, lec1);
      const int px1  = __shfl(ehi, lec1);
      const bool ok1 = le1 < lim;

      float4 f0 = *(const float4*)(vals + (size_t)eid0 * 64 + nn * 4);  // coalesced 1KB/slot
      float4 f1 = *(const float4*)(vals + (size_t)eid1 * 64 + nn * 4);
      const ushort* xr0 = xt + (size_t)px0 * 256;
      const ushort* xr1 = xt + (size_t)px1 * 256;
      FragU alo0, ahi0, alo1, ahi1;
      alo0.u4 = *(const uint4*)(xr0 + nn * 8);                // batch = nn
      ahi0.u4 = *(const uint4*)(xr0 + 128 + nn * 8);          // batch = nn+16
      alo1.u4 = *(const uint4*)(xr1 + nn * 8);
      ahi1.u4 = *(const uint4*)(xr1 + 128 + nn * 8);

      // --- convert + zero invalid edges (keeps B exactly 0) ---
      unsigned u00 = pack2bf(f0.x, f0.y), u01 = pack2bf(f0.z, f0.w);
      unsigned u10 = pack2bf(f1.x, f1.y), u11 = pack2bf(f1.z, f1.w);
      if (!ok0) { u00 = 0; u01 = 0; }
      if (!ok1) { u10 = 0; u11 = 0; }

      // --- in-wave transpose to B layout: lane nn <- column j=nn ---
      FragU b0, b1;
#pragma unroll
      for (int i = 0; i < 8; ++i) {
        unsigned t00 = (unsigned)__shfl((int)u00, sidx[i]);
        unsigned t01 = (unsigned)__shfl((int)u01, sidx[i]);
        unsigned w0 = selW ? t01 : t00;
        b0.us[i] = selH ? (ushort)(w0 >> 16) : (ushort)(w0 & 0xffffu);
        unsigned t10 = (unsigned)__shfl((int)u10, sidx[i]);
        unsigned t11 = (unsigned)__shfl((int)u11, sidx[i]);
        unsigned w1 = selW ? t11 : t10;
        b1.us[i] = selH ? (ushort)(w1 >> 16) : (ushort)(w1 & 0xffffu);
      }

      acc0 = __builtin_amdgcn_mfma_f32_16x16x32_bf16(alo0.v, b0.v, acc0, 0, 0, 0);
      acc1 = __builtin_amdgcn_mfma_f32_16x16x32_bf16(ahi0.v, b0.v, acc1, 0, 0, 0);
      acc0 = __builtin_amdgcn_mfma_f32_16x16x32_bf16(alo1.v, b1.v, acc0, 0, 0, 0);
      acc1 = __builtin_amdgcn_mfma_f32_16x16x32_bf16(ahi1.v, b1.v, acc1, 0, 0, 0);
    }
  }

  // Stage C into LDS: C/D col(j) = lane&15 (only j<8 meaningful), row(b) =
  // quad*4 + reg (acc0) / 16 + quad*4 + reg (acc1). Block-local col = w*8+j.
  if (nn < 8) {
#pragma unroll
    for (int r = 0; r < 4; ++r) {
      so[quad * 4 + r][w * 8 + nn] = acc0[r];
      so[16 + quad * 4 + r][w * 8 + nn] = acc1[r];
    }
  }
  __syncthreads();

  // Coalesced write: 32 rows x 128B contiguous (full lines), bias fused.
  {
    const int row = t >> 3;            // 0..31
    const int c4 = (t & 7) * 4;        // 0,4,...,28
    const int bcol = blockIdx.x * 32 + c4;
    float4 v;
    v.x = so[row][c4 + 0] + bias[bcol + 0];
    v.y = so[row][c4 + 1] + bias[bcol + 1];
    v.z = so[row][c4 + 2] + bias[bcol + 2];
    v.w = so[row][c4 + 3] + bias[bcol + 3];
    *(float4*)&out[(size_t)row * SIZE2 + bcol] = v;
  }
}

extern "C" void kernel_launch(void* const* d_in, const int* in_sizes, int n_in,
                              void* d_out, int out_size, void* d_ws, size_t ws_size,
                              hipStream_t stream) {
  const float* x    = (const float*)d_in[0];
  const float* vals = (const float*)d_in[1];
  const float* bias = (const float*)d_in[2];
  const int*   idxs = (const int*)d_in[3];
  float* out = (float*)d_out;

  int* ws = (int*)d_ws;
  int* cursor = ws + WS_CURSOR;
  unsigned long long* recs = (unsigned long long*)(ws + WS_RECS);
  ushort* xt = (ushort*)(ws + WS_XT);

  hipMemsetAsync(cursor, 0, N_NODES * CSTRIDE * sizeof(int), stream);

  build_kernel<<<NE / 256, 256, 0, stream>>>(x, idxs, cursor, recs, xt);
  gather_mfma_kernel<<<N_NODES / 4, 256, 0, stream>>>(xt, vals, bias, cursor, recs, out);
}